// Round 7
// baseline (579.793 us; speedup 1.0000x reference)
//
#include <hip/hip_runtime.h>
#include <hip/hip_bf16.h>

// Problem constants
constexpr int B_ = 2, S_ = 1024, H_ = 2048;
constexpr int NH_ = 16, NKV_ = 8, HD_ = 128, GROUPS_ = 2;
constexpr int TOPK_ = 409;  // int(0.4 * 1024)
constexpr int QSTRIDE = NH_ * HD_;   // 2048
constexpr int KSTRIDE = NKV_ * HD_;  // 1024
constexpr int QB_ = 16;              // queries per attention block (full MFMA M)

typedef __attribute__((ext_vector_type(8))) short short8;
typedef __attribute__((ext_vector_type(4))) float f32x4;
typedef __attribute__((ext_vector_type(4))) unsigned u32x4;
typedef __attribute__((ext_vector_type(2))) unsigned u32x2;

__device__ inline unsigned fkey(float x) {
  unsigned u = __float_as_uint(x);
  return (u & 0x80000000u) ? ~u : (u | 0x80000000u);
}
// float -> (hi bf16 << 16) | lo bf16   (RNE split: x ~= hi + lo)
__device__ inline unsigned packsplit(float x) {
  unsigned u = __float_as_uint(x);
  unsigned r = (u + 0x7FFFu + ((u >> 16) & 1u)) & 0xFFFF0000u;
  float rem = x - __uint_as_float(r);
  unsigned v = __float_as_uint(rem);
  unsigned l = (v + 0x7FFFu + ((v >> 16) & 1u)) >> 16;
  return r | l;
}

// perm selectors: dst = {src1.b2,src1.b3,src0.b2,src0.b3} (hi) / low bytes (lo)
#define PERM_HI 0x07060302u
#define PERM_LO 0x05040100u

// 8 packed dwords (16B-aligned LDS/global) -> hi/lo bf16 fragments
__device__ inline void unpack8(const unsigned* p, short8& hi, short8& lo) {
  u32x4 w0 = *(const u32x4*)p;
  u32x4 w1 = *(const u32x4*)(p + 4);
  u32x4 h, l;
  h.x = __builtin_amdgcn_perm(w0.y, w0.x, PERM_HI);
  h.y = __builtin_amdgcn_perm(w0.w, w0.z, PERM_HI);
  h.z = __builtin_amdgcn_perm(w1.y, w1.x, PERM_HI);
  h.w = __builtin_amdgcn_perm(w1.w, w1.z, PERM_HI);
  l.x = __builtin_amdgcn_perm(w0.y, w0.x, PERM_LO);
  l.y = __builtin_amdgcn_perm(w0.w, w0.z, PERM_LO);
  l.z = __builtin_amdgcn_perm(w1.y, w1.x, PERM_LO);
  l.w = __builtin_amdgcn_perm(w1.w, w1.z, PERM_LO);
  hi = *(short8*)&h;
  lo = *(short8*)&l;
}
// same, from two registers (globals already loaded)
__device__ inline void unpack8r(u32x4 w0, u32x4 w1, short8& hi, short8& lo) {
  u32x4 h, l;
  h.x = __builtin_amdgcn_perm(w0.y, w0.x, PERM_HI);
  h.y = __builtin_amdgcn_perm(w0.w, w0.z, PERM_HI);
  h.z = __builtin_amdgcn_perm(w1.y, w1.x, PERM_HI);
  h.w = __builtin_amdgcn_perm(w1.w, w1.z, PERM_HI);
  l.x = __builtin_amdgcn_perm(w0.y, w0.x, PERM_LO);
  l.y = __builtin_amdgcn_perm(w0.w, w0.z, PERM_LO);
  l.z = __builtin_amdgcn_perm(w1.y, w1.x, PERM_LO);
  l.w = __builtin_amdgcn_perm(w1.w, w1.z, PERM_LO);
  hi = *(short8*)&h;
  lo = *(short8*)&l;
}

// ---------------------------------------------------------------------------
// Pack fp32 inputs to split-bf16 dwords (hi|lo), one pass, bit-identical to
// the per-block conversion it replaces. Grid-stride over all 16M elements.
// ---------------------------------------------------------------------------
__global__ __launch_bounds__(256) void pack_inputs(
    const float* __restrict__ hidden, const float* __restrict__ wq,
    const float* __restrict__ wk, const float* __restrict__ wv,
    const float* __restrict__ wo, unsigned* __restrict__ hidP,
    unsigned* __restrict__ wqP, unsigned* __restrict__ wkP,
    unsigned* __restrict__ wvP, unsigned* __restrict__ woP) {
  size_t gid = (size_t)blockIdx.x * 256 + threadIdx.x;  // float4 index
  const float* src;
  unsigned* dst;
  size_t off;
  if (gid < 1048576) { src = hidden; dst = hidP; off = gid; }
  else if (gid < 2097152) { src = wq; dst = wqP; off = gid - 1048576; }
  else if (gid < 2621440) { src = wk; dst = wkP; off = gid - 2097152; }
  else if (gid < 3145728) { src = wv; dst = wvP; off = gid - 2621440; }
  else { src = wo; dst = woP; off = gid - 3145728; }
  float4 x = *(const float4*)&src[off * 4];
  u32x4 p;
  p.x = packsplit(x.x);
  p.y = packsplit(x.y);
  p.z = packsplit(x.z);
  p.w = packsplit(x.w);
  *(u32x4*)&dst[off * 4] = p;
}

// ---------------------------------------------------------------------------
// Split-precision bf16 MFMA GEMM body, PACKED inputs (hi|lo dwords).
// Tile: (TI*32) x 128, BK=32, 256 threads (4 waves). Double-buffered LDS,
// one barrier per K-step, register prefetch. Conversion is now 4 perms +
// 2 stores per 4 elements (was ~28 VALU). Chunk-swizzled LDS (2-way reads).
// MFMA order / values bit-identical to the fp32-converting version.
// ---------------------------------------------------------------------------
template <int TI>
__device__ __forceinline__ void gemm_split_body(
    const unsigned* __restrict__ A, const unsigned* __restrict__ W,
    const float* __restrict__ bias, float* __restrict__ C, int ldc, int c0,
    int K, int m0) {
  __shared__ unsigned short Ah[2][TI * 32 * 32];
  __shared__ unsigned short Al[2][TI * 32 * 32];
  __shared__ unsigned short Wh[2][128 * 32];
  __shared__ unsigned short Wl[2][128 * 32];
  const int tid = threadIdx.x;
  const int lane = tid & 63, wid = tid >> 6;
  const int wrow = (wid >> 1) * (TI * 16), wcol = (wid & 1) * 64;
  const int fm = lane & 15, quad = lane >> 4;
  const int srow = tid >> 3;        // 0..31
  const int skq = (tid & 7) * 4;    // 0,4,..,28
  f32x4 acc[TI][4] = {};
  u32x4 avr[TI], wvr[4];

  auto loadAW = [&](int k0) {
#pragma unroll
    for (int r = 0; r < TI; ++r)
      avr[r] = *(const u32x4*)&A[(size_t)(m0 + srow + 32 * r) * K + k0 + skq];
#pragma unroll
    for (int r = 0; r < 4; ++r)
      wvr[r] = *(const u32x4*)&W[(size_t)(srow + 32 * r) * K + k0 + skq];
  };
  auto convWrite = [&](int buf) {
#pragma unroll
    for (int r = 0; r < TI; ++r) {
      const int row = srow + 32 * r;
      const int off =
          row * 32 + ((((skq >> 3) ^ ((row >> 1) & 3)) << 3) | (skq & 7));
      u32x4 w = avr[r];
      u32x2 hi, lo;
      hi.x = __builtin_amdgcn_perm(w.y, w.x, PERM_HI);
      hi.y = __builtin_amdgcn_perm(w.w, w.z, PERM_HI);
      lo.x = __builtin_amdgcn_perm(w.y, w.x, PERM_LO);
      lo.y = __builtin_amdgcn_perm(w.w, w.z, PERM_LO);
      *(u32x2*)&Ah[buf][off] = hi;
      *(u32x2*)&Al[buf][off] = lo;
    }
#pragma unroll
    for (int r = 0; r < 4; ++r) {
      const int row = srow + 32 * r;
      const int off =
          row * 32 + ((((skq >> 3) ^ ((row >> 1) & 3)) << 3) | (skq & 7));
      u32x4 w = wvr[r];
      u32x2 hi, lo;
      hi.x = __builtin_amdgcn_perm(w.y, w.x, PERM_HI);
      hi.y = __builtin_amdgcn_perm(w.w, w.z, PERM_HI);
      lo.x = __builtin_amdgcn_perm(w.y, w.x, PERM_LO);
      lo.y = __builtin_amdgcn_perm(w.w, w.z, PERM_LO);
      *(u32x2*)&Wh[buf][off] = hi;
      *(u32x2*)&Wl[buf][off] = lo;
    }
  };

  loadAW(0);
  convWrite(0);
  __syncthreads();
  int cur = 0;
  for (int k0 = 0; k0 < K; k0 += 32) {
    const bool more = (k0 + 32) < K;
    if (more) loadAW(k0 + 32);  // issue early; consumed by convWrite below
    short8 ah[TI], al[TI], bh[4], bl[4];
#pragma unroll
    for (int ti = 0; ti < TI; ++ti) {
      const int r = wrow + 16 * ti + fm;
      const int off = r * 32 + ((quad ^ ((r >> 1) & 3)) << 3);
      ah[ti] = *(const short8*)&Ah[cur][off];
      al[ti] = *(const short8*)&Al[cur][off];
    }
#pragma unroll
    for (int tj = 0; tj < 4; ++tj) {
      const int r = wcol + 16 * tj + fm;
      const int off = r * 32 + ((quad ^ ((r >> 1) & 3)) << 3);
      bh[tj] = *(const short8*)&Wh[cur][off];
      bl[tj] = *(const short8*)&Wl[cur][off];
    }
#pragma unroll
    for (int ti = 0; ti < TI; ++ti)
#pragma unroll
      for (int tj = 0; tj < 4; ++tj) {
        acc[ti][tj] = __builtin_amdgcn_mfma_f32_16x16x32_bf16(
            ah[ti], bh[tj], acc[ti][tj], 0, 0, 0);
        acc[ti][tj] = __builtin_amdgcn_mfma_f32_16x16x32_bf16(
            ah[ti], bl[tj], acc[ti][tj], 0, 0, 0);
        acc[ti][tj] = __builtin_amdgcn_mfma_f32_16x16x32_bf16(
            al[ti], bh[tj], acc[ti][tj], 0, 0, 0);
      }
    if (more) convWrite(cur ^ 1);
    __syncthreads();
    cur ^= 1;
  }
#pragma unroll
  for (int tj = 0; tj < 4; ++tj) {
    float bsv = bias[wcol + 16 * tj + fm];
#pragma unroll
    for (int ti = 0; ti < TI; ++ti) {
      int mrow = m0 + wrow + 16 * ti + quad * 4;
      int ncol = c0 + wcol + 16 * tj + fm;
#pragma unroll
      for (int reg = 0; reg < 4; ++reg)
        C[(size_t)(mrow + reg) * ldc + ncol] = acc[ti][tj][reg] + bsv;
    }
  }
}

// Fused QKV projection (packed inputs): N = [q 0..2048)[k ..3072)[v ..4096)
__global__ __launch_bounds__(256) void gemm_qkv(
    const unsigned* __restrict__ hidP, const unsigned* __restrict__ wqP,
    const float* __restrict__ bq, const unsigned* __restrict__ wkP,
    const float* __restrict__ bk, const unsigned* __restrict__ wvP,
    const float* __restrict__ bv, float* __restrict__ q, float* __restrict__ k,
    float* __restrict__ v) {
  const int n0 = blockIdx.x * 128, m0 = blockIdx.y * 128;
  if (n0 < QSTRIDE) {
    gemm_split_body<4>(hidP, wqP + (size_t)n0 * H_, bq + n0, q, QSTRIDE, n0,
                       H_, m0);
  } else if (n0 < QSTRIDE + KSTRIDE) {
    int nn = n0 - QSTRIDE;
    gemm_split_body<4>(hidP, wkP + (size_t)nn * H_, bk + nn, k, KSTRIDE, nn,
                       H_, m0);
  } else {
    int nn = n0 - QSTRIDE - KSTRIDE;
    gemm_split_body<4>(hidP, wvP + (size_t)nn * H_, bv + nn, v, KSTRIDE, nn,
                       H_, m0);
  }
}

// Out-projection (packed A from attn epilogue, packed wo)
template <int TI>
__global__ __launch_bounds__(256) void gemm_split_k(
    const unsigned* __restrict__ A, const unsigned* __restrict__ W,
    const float* __restrict__ bias, float* __restrict__ C, int N, int K) {
  const int n0 = blockIdx.x * 128, m0 = blockIdx.y * (TI * 32);
  gemm_split_body<TI>(A, W + (size_t)n0 * K, bias + n0, C, N, n0, K, m0);
}

// ---------------------------------------------------------------------------
// RoPE (q,k only) + split-pack IN PLACE as (hi<<16|lo) dwords.
// grid (S, B), block 256. v handled by vtrans.
// ---------------------------------------------------------------------------
__global__ __launch_bounds__(256) void rope_pack(float* __restrict__ qtmp,
                                                 float* __restrict__ ktmp,
                                                 const int* __restrict__ pos_ids) {
  const int s = blockIdx.x, b = blockIdx.y;
  const int t = threadIdx.x;
  __shared__ float fsh[64];
  if (t < 64) fsh[t] = (float)(1.0 / pow(1.0e6, (double)t / 64.0));
  __syncthreads();
  const int pos = pos_ids[b * S_ + s];
#pragma unroll
  for (int it = 0; it < 6; ++it) {
    const int p = t + 256 * it;   // 0..1535 (slots 0..23: q then k)
    const int slot = p >> 6;      // uniform per wave
    const int d = p & 63;
    float* base = (slot < NH_)
                      ? qtmp + (size_t)(b * S_ + s) * QSTRIDE + slot * HD_
                      : ktmp + (size_t)(b * S_ + s) * KSTRIDE + (slot - NH_) * HD_;
    float x = base[d], y = base[d + 64];
    unsigned* up = (unsigned*)base;
    float ang = (float)pos * fsh[d];
    float c = cosf(ang), sn = sinf(ang);
    up[d] = packsplit(x * c - y * sn);
    up[d + 64] = packsplit(y * c + x * sn);
  }
}

// ---------------------------------------------------------------------------
// V transpose+pack: vtmp fp32 [b][s][g][d] -> vT packed u32 [b][g][d][s].
// grid (S/64, NKV, B), block 256.
// ---------------------------------------------------------------------------
__global__ __launch_bounds__(256) void vtrans(const float* __restrict__ vtmp,
                                              unsigned* __restrict__ vT) {
  const int s0 = blockIdx.x * 64;
  const int g = blockIdx.y, b = blockIdx.z;
  __shared__ unsigned tile[64][133];
  const int t = threadIdx.x;
  {
    const int row = t >> 5;        // 0..7
    const int c4 = (t & 31) * 4;   // dword col
    for (int r = 0; r < 64; r += 8) {
      const float* src =
          vtmp + ((size_t)(b * S_ + s0 + row + r) * NKV_ + g) * HD_ + c4;
      float4 xv = *(const float4*)src;
      tile[row + r][c4 + 0] = packsplit(xv.x);
      tile[row + r][c4 + 1] = packsplit(xv.y);
      tile[row + r][c4 + 2] = packsplit(xv.z);
      tile[row + r][c4 + 3] = packsplit(xv.w);
    }
  }
  __syncthreads();
  {
    const int tok4 = (t & 15) * 4;  // 0..60
    const int d0 = t >> 4;          // 0..15
    for (int dd = 0; dd < 128; dd += 16) {
      const int dim = d0 + dd;
      u32x4 o;
      o.x = tile[tok4 + 0][dim];
      o.y = tile[tok4 + 1][dim];
      o.z = tile[tok4 + 2][dim];
      o.w = tile[tok4 + 3][dim];
      *(u32x4*)&vT[(((size_t)(b * NKV_ + g) * HD_ + dim) * S_) + s0 + tok4] = o;
    }
  }
}

// ---------------------------------------------------------------------------
// Sparse attention v10 (MFMA): one block per (b, h, 16 queries), 512 threads.
// - QK^T/PV: rolled 4x2-tile loops with static-named register double-buffer
//   (small code footprint; prefetch preserved).
// - Exact top-k: 32-round bisection with PER-LANE VALU predicate counts
//   (both queries packed in one dword) + shfl_xor butterfly — no scalar-ALU
//   counting chains, no LDS atomics. Same threshold semantics.
// - Epilogue writes output PRE-PACKED (hi|lo) for the out-projection.
// Bit-identical numerics to v9.
// ---------------------------------------------------------------------------
constexpr int SCW = 1030;   // sc row stride (pad: 1024+6)

__global__ __launch_bounds__(512, 4) void attn_kernel(
    unsigned* __restrict__ qpk, const unsigned* __restrict__ kpk,
    const unsigned* __restrict__ vTpk) {
  const int q0 = blockIdx.x * QB_;
  const int h = blockIdx.y, b = blockIdx.z, g = h / GROUPS_;
  const int t = threadIdx.x, lane = t & 63, wid = t >> 6;  // wid 0..7
  const int fm = lane & 15, quad = lane >> 4;

  __shared__ float sc[QB_ * SCW];       // 65.9 KB: fp32 scores -> packed probs
  __shared__ float redmx[8][QB_];
  __shared__ float Zsh[QB_];
  const float scale = 0.08838834764831845f;  // 1/sqrt(128)

  // ---- Q A-fragments straight from global (row fm = query within block) ----
  short8 qh[4], ql[4];
  {
    const unsigned* qrow =
        qpk + (size_t)(b * S_ + q0 + fm) * QSTRIDE + h * HD_;
#pragma unroll
    for (int ks = 0; ks < 4; ++ks) {
      u32x4 a0 = *(const u32x4*)&qrow[ks * 32 + quad * 8];
      u32x4 a1 = *(const u32x4*)&qrow[ks * 32 + quad * 8 + 4];
      unpack8r(a0, a1, qh[ks], ql[ks]);
    }
  }

  // ---- QK^T over 8 tiles of 128 keys; rolled 2-tile register dbuf ----
  const unsigned* kg = kpk + (size_t)(b * S_) * KSTRIDE + g * HD_;
  const int krow = wid * 16 + fm;  // key within tile
  const unsigned* kr0 = kg + (size_t)krow * KSTRIDE;
  u32x4 ka[8], kb[8];
  f32x4 mxacc = {-1e30f, -1e30f, -1e30f, -1e30f};

  auto k_load = [&](u32x4* kreg, int tile) {
    const unsigned* kr = kr0 + (size_t)tile * 128 * KSTRIDE;
#pragma unroll
    for (int ks = 0; ks < 4; ++ks) {
      kreg[2 * ks] = *(const u32x4*)&kr[ks * 32 + quad * 8];
      kreg[2 * ks + 1] = *(const u32x4*)&kr[ks * 32 + quad * 8 + 4];
    }
  };
  auto qk_tile = [&](const u32x4* kreg, int tile) {
    f32x4 acc = {0.f, 0.f, 0.f, 0.f};
#pragma unroll
    for (int ks = 0; ks < 4; ++ks) {
      short8 bh, bl;
      unpack8r(kreg[2 * ks], kreg[2 * ks + 1], bh, bl);
      acc = __builtin_amdgcn_mfma_f32_16x16x32_bf16(qh[ks], bh, acc, 0, 0, 0);
      acc = __builtin_amdgcn_mfma_f32_16x16x32_bf16(qh[ks], bl, acc, 0, 0, 0);
      acc = __builtin_amdgcn_mfma_f32_16x16x32_bf16(ql[ks], bh, acc, 0, 0, 0);
    }
    const int key = tile * 128 + krow;
#pragma unroll
    for (int reg = 0; reg < 4; ++reg) {
      float sval = acc[reg] * scale;
      sc[(quad * 4 + reg) * SCW + key] = sval;
      mxacc[reg] = fmaxf(mxacc[reg], sval);
    }
  };

  k_load(ka, 0);
#pragma unroll 1
  for (int tp = 0; tp < 4; ++tp) {
    k_load(kb, 2 * tp + 1);
    qk_tile(ka, 2 * tp);
    if (tp < 3) k_load(ka, 2 * tp + 2);
    qk_tile(kb, 2 * tp + 1);
  }

  // per-wave row max: reduce across fm lanes (quad bits untouched)
#pragma unroll
  for (int o = 1; o < 16; o <<= 1) {
    mxacc[0] = fmaxf(mxacc[0], __shfl_xor(mxacc[0], o));
    mxacc[1] = fmaxf(mxacc[1], __shfl_xor(mxacc[1], o));
    mxacc[2] = fmaxf(mxacc[2], __shfl_xor(mxacc[2], o));
    mxacc[3] = fmaxf(mxacc[3], __shfl_xor(mxacc[3], o));
  }
  if (fm == 0) {
#pragma unroll
    for (int reg = 0; reg < 4; ++reg) redmx[wid][quad * 4 + reg] = mxacc[reg];
  }
  __syncthreads();  // barrier 1: sc + redmx complete (all waves)

  // ---- issue V tile-0 prefetch; latency hides under the select ----
  const int dim = wid * 16 + fm;  // output dim for this lane
  const unsigned* vTr = vTpk + ((size_t)(b * NKV_ + g) * HD_ + dim) * S_;
  u32x4 va[8], vb[8];
  auto v_load = [&](u32x4* vreg, int tile) {
    const unsigned* vr = vTr + tile * 128;
#pragma unroll
    for (int ks = 0; ks < 4; ++ks) {
      vreg[2 * ks] = *(const u32x4*)&vr[ks * 32 + quad * 8];
      vreg[2 * ks + 1] = *(const u32x4*)&vr[ks * 32 + quad * 8 + 4];
    }
  };
  v_load(va, 0);

  // ---- exact top-k threshold: 32-round bisection, per-lane VALU counts ----
  // T = max{T : #(fkey >= T) >= k}  (k-th largest key; ties included)
  unsigned curA = 0u, curB = 0u;
  {
    unsigned uvA[16], uvB[16];
#pragma unroll
    for (int j = 0; j < 16; ++j)
      uvA[j] = fkey(sc[(2 * wid) * SCW + lane + 64 * j]);
#pragma unroll
    for (int j = 0; j < 16; ++j)
      uvB[j] = fkey(sc[(2 * wid + 1) * SCW + lane + 64 * j]);
#pragma unroll 1
    for (int bit = 31; bit >= 0; --bit) {
      const unsigned cA = curA | (1u << bit), cB = curB | (1u << bit);
      unsigned cntA = 0, cntB = 0;
#pragma unroll
      for (int j = 0; j < 16; ++j) cntA += (uvA[j] >= cA) ? 1u : 0u;
#pragma unroll
      for (int j = 0; j < 16; ++j) cntB += (uvB[j] >= cB) ? 1u : 0u;
      unsigned cnt = cntA + (cntB << 16);
#pragma unroll
      for (int o = 1; o < 64; o <<= 1) cnt += __shfl_xor(cnt, o);
      if ((cnt & 0xFFFFu) >= (unsigned)TOPK_) curA = cA;
      if ((cnt >> 16) >= (unsigned)TOPK_) curB = cB;
    }
  }
  const unsigned pref = (lane >= 32) ? curB : curA;  // row qi = t>>5

  // ---- masked softmax numerators; pack P in place as hi|lo dwords ----
  {
    const int qi = t >> 5, li = t & 31;  // 32 threads per query row
    const float mx =
        fmaxf(fmaxf(fmaxf(redmx[0][qi], redmx[1][qi]),
                    fmaxf(redmx[2][qi], redmx[3][qi])),
              fmaxf(fmaxf(redmx[4][qi], redmx[5][qi]),
                    fmaxf(redmx[6][qi], redmx[7][qi])));
    unsigned* scp = (unsigned*)&sc[qi * SCW];
    float zloc = 0.f;
#pragma unroll 2
    for (int j = 0; j < 8; ++j) {
      int i4 = li * 4 + 128 * j;
      f32x4 sv = *(const f32x4*)&sc[qi * SCW + i4];
      u32x4 pk;
      float p0 = (fkey(sv.x) >= pref) ? __expf(sv.x - mx) : 0.0f;
      float p1 = (fkey(sv.y) >= pref) ? __expf(sv.y - mx) : 0.0f;
      float p2 = (fkey(sv.z) >= pref) ? __expf(sv.z - mx) : 0.0f;
      float p3 = (fkey(sv.w) >= pref) ? __expf(sv.w - mx) : 0.0f;
      zloc += p0 + p1 + p2 + p3;
      pk.x = packsplit(p0); pk.y = packsplit(p1);
      pk.z = packsplit(p2); pk.w = packsplit(p3);
      *(u32x4*)&scp[i4] = pk;
    }
#pragma unroll
    for (int off = 1; off < 32; off <<= 1) zloc += __shfl_xor(zloc, off);
    if (li == 0) Zsh[qi] = zloc;
  }
  __syncthreads();  // barrier 2: packed P + Zsh visible to all waves

  // ---- P.V over 8 tiles; rolled 2-tile register dbuf (V^T contiguous) ----
  const unsigned* scp2 = (const unsigned*)sc;
  f32x4 oacc = {0.f, 0.f, 0.f, 0.f};
  auto pv_tile = [&](const u32x4* vreg, int tile) {
#pragma unroll
    for (int ks = 0; ks < 4; ++ks) {
      short8 ph, pl;
      unpack8(&scp2[fm * SCW + tile * 128 + ks * 32 + quad * 8], ph, pl);
      short8 vh, vl;
      unpack8r(vreg[2 * ks], vreg[2 * ks + 1], vh, vl);
      oacc = __builtin_amdgcn_mfma_f32_16x16x32_bf16(ph, vh, oacc, 0, 0, 0);
      oacc = __builtin_amdgcn_mfma_f32_16x16x32_bf16(ph, vl, oacc, 0, 0, 0);
      oacc = __builtin_amdgcn_mfma_f32_16x16x32_bf16(pl, vh, oacc, 0, 0, 0);
    }
  };
#pragma unroll 1
  for (int tp = 0; tp < 4; ++tp) {
    v_load(vb, 2 * tp + 1);
    pv_tile(va, 2 * tp);
    if (tp < 3) v_load(va, 2 * tp + 2);
    pv_tile(vb, 2 * tp + 1);
  }

  // ---- epilogue: write PACKED output (feeds packed out-projection) ----
#pragma unroll
  for (int reg = 0; reg < 4; ++reg) {
    const int q = quad * 4 + reg;
    const float invZ = 1.0f / Zsh[q];  // Z >= 1 structurally
    unsigned* outp = qpk + (size_t)(b * S_ + q0 + q) * QSTRIDE + h * HD_;
    outp[dim] = packsplit(oacc[reg] * invZ);
  }
}

// ---------------------------------------------------------------------------
extern "C" void kernel_launch(void* const* d_in, const int* in_sizes, int n_in,
                              void* d_out, int out_size, void* d_ws,
                              size_t ws_size, hipStream_t stream) {
  // All tensors are float32 per the reference; position_ids is int32.
  const float* hidden = (const float*)d_in[0];
  const float* wq = (const float*)d_in[1];
  const float* bq = (const float*)d_in[2];
  const float* wk = (const float*)d_in[3];
  const float* bk = (const float*)d_in[4];
  const float* wv = (const float*)d_in[5];
  const float* bv = (const float*)d_in[6];
  const float* wo = (const float*)d_in[7];
  const float* bo = (const float*)d_in[8];
  const int* pos = (const int*)d_in[9];
  float* out = (float*)d_out;

  char* ws = (char*)d_ws;
  // ws layout (96 MB):
  //  0..16  hidP   (packed hidden)
  // 16..32  wqP    (packed wq)      -> reused as vT (8 MB) after gemm_qkv
  // 32..40  wkP    (packed wk)
  // 40..48  wvP    (packed wv)
  // 48..64  woP    (packed wo; live until out-proj)
  // 64..80  qtmp   (fp32 q -> rope-packed -> attn writes packed out in place)
  // 80..88  ktmp   (fp32 k -> rope-packed)
  // 88..96  vtmp   (fp32 v)
  unsigned* hidP = (unsigned*)(ws);
  unsigned* wqP = (unsigned*)(ws + ((size_t)16 << 20));
  unsigned* wkP = (unsigned*)(ws + ((size_t)32 << 20));
  unsigned* wvP = (unsigned*)(ws + ((size_t)40 << 20));
  unsigned* woP = (unsigned*)(ws + ((size_t)48 << 20));
  float* qtmp = (float*)(ws + ((size_t)64 << 20));
  float* ktmp = (float*)(ws + ((size_t)80 << 20));
  float* vtmp = (float*)(ws + ((size_t)88 << 20));
  unsigned* vT = (unsigned*)(ws + ((size_t)16 << 20));  // over wqP (dead)

  dim3 blk(256);
  // One-pass split-bf16 packing of all GEMM inputs (bit-identical math)
  pack_inputs<<<dim3(16384), blk, 0, stream>>>(hidden, wq, wk, wv, wo, hidP,
                                               wqP, wkP, wvP, woP);
  // Fused QKV projection (packed inputs): grid 32x16 = 512 blocks (2/CU)
  gemm_qkv<<<dim3(32, 16), blk, 0, stream>>>(hidP, wqP, bq, wkP, bk, wvP, bv,
                                             qtmp, ktmp, vtmp);
  // RoPE + in-place split-pack of q, k
  rope_pack<<<dim3(S_, B_), blk, 0, stream>>>(qtmp, ktmp, pos);
  // V transpose + pack (into the dead wqP region)
  vtrans<<<dim3(S_ / 64, NKV_, B_), blk, 0, stream>>>(vtmp, vT);
  // MFMA sparse attention: 16 queries/block, 512 threads, grid 64x16x2
  attn_kernel<<<dim3(S_ / QB_, NH_, B_), dim3(512), 0, stream>>>(
      (unsigned*)qtmp, (const unsigned*)ktmp, vT);
  // Output projection (packed A + packed wo): grid 16x32 = 512 blocks
  gemm_split_k<2><<<dim3(H_ / 128, (B_ * S_) / 64), blk, 0, stream>>>(
      (const unsigned*)qtmp, woP, bo, out, H_, H_);
}

// Round 8
// 550.576 us; speedup vs baseline: 1.0531x; 1.0531x over previous
//
#include <hip/hip_runtime.h>
#include <hip/hip_bf16.h>

// Problem constants
constexpr int B_ = 2, S_ = 1024, H_ = 2048;
constexpr int NH_ = 16, NKV_ = 8, HD_ = 128, GROUPS_ = 2;
constexpr int TOPK_ = 409;  // int(0.4 * 1024)
constexpr int QSTRIDE = NH_ * HD_;   // 2048
constexpr int KSTRIDE = NKV_ * HD_;  // 1024
constexpr int QB_ = 16;              // queries per attention block (full MFMA M)

typedef __attribute__((ext_vector_type(8))) short short8;
typedef __attribute__((ext_vector_type(4))) float f32x4;
typedef __attribute__((ext_vector_type(4))) unsigned u32x4;
typedef __attribute__((ext_vector_type(2))) unsigned u32x2;

__device__ inline unsigned fkey(float x) {
  unsigned u = __float_as_uint(x);
  return (u & 0x80000000u) ? ~u : (u | 0x80000000u);
}
// float -> (hi bf16 << 16) | lo bf16   (RNE split: x ~= hi + lo)
__device__ inline unsigned packsplit(float x) {
  unsigned u = __float_as_uint(x);
  unsigned r = (u + 0x7FFFu + ((u >> 16) & 1u)) & 0xFFFF0000u;
  float rem = x - __uint_as_float(r);
  unsigned v = __float_as_uint(rem);
  unsigned l = (v + 0x7FFFu + ((v >> 16) & 1u)) >> 16;
  return r | l;
}

// perm selectors: dst = {src1.b2,src1.b3,src0.b2,src0.b3} (hi) / low bytes (lo)
#define PERM_HI 0x07060302u
#define PERM_LO 0x05040100u

// 8 packed dwords (16B-aligned LDS/global) -> hi/lo bf16 fragments
__device__ inline void unpack8(const unsigned* p, short8& hi, short8& lo) {
  u32x4 w0 = *(const u32x4*)p;
  u32x4 w1 = *(const u32x4*)(p + 4);
  u32x4 h, l;
  h.x = __builtin_amdgcn_perm(w0.y, w0.x, PERM_HI);
  h.y = __builtin_amdgcn_perm(w0.w, w0.z, PERM_HI);
  h.z = __builtin_amdgcn_perm(w1.y, w1.x, PERM_HI);
  h.w = __builtin_amdgcn_perm(w1.w, w1.z, PERM_HI);
  l.x = __builtin_amdgcn_perm(w0.y, w0.x, PERM_LO);
  l.y = __builtin_amdgcn_perm(w0.w, w0.z, PERM_LO);
  l.z = __builtin_amdgcn_perm(w1.y, w1.x, PERM_LO);
  l.w = __builtin_amdgcn_perm(w1.w, w1.z, PERM_LO);
  hi = *(short8*)&h;
  lo = *(short8*)&l;
}
// same, from two registers (globals already loaded)
__device__ inline void unpack8r(u32x4 w0, u32x4 w1, short8& hi, short8& lo) {
  u32x4 h, l;
  h.x = __builtin_amdgcn_perm(w0.y, w0.x, PERM_HI);
  h.y = __builtin_amdgcn_perm(w0.w, w0.z, PERM_HI);
  h.z = __builtin_amdgcn_perm(w1.y, w1.x, PERM_HI);
  h.w = __builtin_amdgcn_perm(w1.w, w1.z, PERM_HI);
  l.x = __builtin_amdgcn_perm(w0.y, w0.x, PERM_LO);
  l.y = __builtin_amdgcn_perm(w0.w, w0.z, PERM_LO);
  l.z = __builtin_amdgcn_perm(w1.y, w1.x, PERM_LO);
  l.w = __builtin_amdgcn_perm(w1.w, w1.z, PERM_LO);
  hi = *(short8*)&h;
  lo = *(short8*)&l;
}

// ---------------------------------------------------------------------------
// Pack fp32 inputs to split-bf16 dwords (hi|lo), one pass, bit-identical to
// the per-block conversion it replaces. Grid-stride over all 16M elements.
// ---------------------------------------------------------------------------
__global__ __launch_bounds__(256) void pack_inputs(
    const float* __restrict__ hidden, const float* __restrict__ wq,
    const float* __restrict__ wk, const float* __restrict__ wv,
    const float* __restrict__ wo, unsigned* __restrict__ hidP,
    unsigned* __restrict__ wqP, unsigned* __restrict__ wkP,
    unsigned* __restrict__ wvP, unsigned* __restrict__ woP) {
  size_t gid = (size_t)blockIdx.x * 256 + threadIdx.x;  // float4 index
  const float* src;
  unsigned* dst;
  size_t off;
  if (gid < 1048576) { src = hidden; dst = hidP; off = gid; }
  else if (gid < 2097152) { src = wq; dst = wqP; off = gid - 1048576; }
  else if (gid < 2621440) { src = wk; dst = wkP; off = gid - 2097152; }
  else if (gid < 3145728) { src = wv; dst = wvP; off = gid - 2621440; }
  else { src = wo; dst = woP; off = gid - 3145728; }
  float4 x = *(const float4*)&src[off * 4];
  u32x4 p;
  p.x = packsplit(x.x);
  p.y = packsplit(x.y);
  p.z = packsplit(x.z);
  p.w = packsplit(x.w);
  *(u32x4*)&dst[off * 4] = p;
}

// ---------------------------------------------------------------------------
// Split-precision bf16 MFMA GEMM body, PACKED inputs (hi|lo dwords).
// Tile: (TI*32) x 128, BK=32, 256 threads (4 waves). Double-buffered LDS,
// one barrier per K-step, register prefetch. Conversion is 4 perms +
// 2 stores per 4 elements. Chunk-swizzled LDS (2-way reads).
// ---------------------------------------------------------------------------
template <int TI>
__device__ __forceinline__ void gemm_split_body(
    const unsigned* __restrict__ A, const unsigned* __restrict__ W,
    const float* __restrict__ bias, float* __restrict__ C, int ldc, int c0,
    int K, int m0) {
  __shared__ unsigned short Ah[2][TI * 32 * 32];
  __shared__ unsigned short Al[2][TI * 32 * 32];
  __shared__ unsigned short Wh[2][128 * 32];
  __shared__ unsigned short Wl[2][128 * 32];
  const int tid = threadIdx.x;
  const int lane = tid & 63, wid = tid >> 6;
  const int wrow = (wid >> 1) * (TI * 16), wcol = (wid & 1) * 64;
  const int fm = lane & 15, quad = lane >> 4;
  const int srow = tid >> 3;        // 0..31
  const int skq = (tid & 7) * 4;    // 0,4,..,28
  f32x4 acc[TI][4] = {};
  u32x4 avr[TI], wvr[4];

  auto loadAW = [&](int k0) {
#pragma unroll
    for (int r = 0; r < TI; ++r)
      avr[r] = *(const u32x4*)&A[(size_t)(m0 + srow + 32 * r) * K + k0 + skq];
#pragma unroll
    for (int r = 0; r < 4; ++r)
      wvr[r] = *(const u32x4*)&W[(size_t)(srow + 32 * r) * K + k0 + skq];
  };
  auto convWrite = [&](int buf) {
#pragma unroll
    for (int r = 0; r < TI; ++r) {
      const int row = srow + 32 * r;
      const int off =
          row * 32 + ((((skq >> 3) ^ ((row >> 1) & 3)) << 3) | (skq & 7));
      u32x4 w = avr[r];
      u32x2 hi, lo;
      hi.x = __builtin_amdgcn_perm(w.y, w.x, PERM_HI);
      hi.y = __builtin_amdgcn_perm(w.w, w.z, PERM_HI);
      lo.x = __builtin_amdgcn_perm(w.y, w.x, PERM_LO);
      lo.y = __builtin_amdgcn_perm(w.w, w.z, PERM_LO);
      *(u32x2*)&Ah[buf][off] = hi;
      *(u32x2*)&Al[buf][off] = lo;
    }
#pragma unroll
    for (int r = 0; r < 4; ++r) {
      const int row = srow + 32 * r;
      const int off =
          row * 32 + ((((skq >> 3) ^ ((row >> 1) & 3)) << 3) | (skq & 7));
      u32x4 w = wvr[r];
      u32x2 hi, lo;
      hi.x = __builtin_amdgcn_perm(w.y, w.x, PERM_HI);
      hi.y = __builtin_amdgcn_perm(w.w, w.z, PERM_HI);
      lo.x = __builtin_amdgcn_perm(w.y, w.x, PERM_LO);
      lo.y = __builtin_amdgcn_perm(w.w, w.z, PERM_LO);
      *(u32x2*)&Wh[buf][off] = hi;
      *(u32x2*)&Wl[buf][off] = lo;
    }
  };

  loadAW(0);
  convWrite(0);
  __syncthreads();
  int cur = 0;
  for (int k0 = 0; k0 < K; k0 += 32) {
    const bool more = (k0 + 32) < K;
    if (more) loadAW(k0 + 32);  // issue early; consumed by convWrite below
    short8 ah[TI], al[TI], bh[4], bl[4];
#pragma unroll
    for (int ti = 0; ti < TI; ++ti) {
      const int r = wrow + 16 * ti + fm;
      const int off = r * 32 + ((quad ^ ((r >> 1) & 3)) << 3);
      ah[ti] = *(const short8*)&Ah[cur][off];
      al[ti] = *(const short8*)&Al[cur][off];
    }
#pragma unroll
    for (int tj = 0; tj < 4; ++tj) {
      const int r = wcol + 16 * tj + fm;
      const int off = r * 32 + ((quad ^ ((r >> 1) & 3)) << 3);
      bh[tj] = *(const short8*)&Wh[cur][off];
      bl[tj] = *(const short8*)&Wl[cur][off];
    }
#pragma unroll
    for (int ti = 0; ti < TI; ++ti)
#pragma unroll
      for (int tj = 0; tj < 4; ++tj) {
        acc[ti][tj] = __builtin_amdgcn_mfma_f32_16x16x32_bf16(
            ah[ti], bh[tj], acc[ti][tj], 0, 0, 0);
        acc[ti][tj] = __builtin_amdgcn_mfma_f32_16x16x32_bf16(
            ah[ti], bl[tj], acc[ti][tj], 0, 0, 0);
        acc[ti][tj] = __builtin_amdgcn_mfma_f32_16x16x32_bf16(
            al[ti], bh[tj], acc[ti][tj], 0, 0, 0);
      }
    if (more) convWrite(cur ^ 1);
    __syncthreads();
    cur ^= 1;
  }
#pragma unroll
  for (int tj = 0; tj < 4; ++tj) {
    float bsv = bias[wcol + 16 * tj + fm];
#pragma unroll
    for (int ti = 0; ti < TI; ++ti) {
      int mrow = m0 + wrow + 16 * ti + quad * 4;
      int ncol = c0 + wcol + 16 * tj + fm;
#pragma unroll
      for (int reg = 0; reg < 4; ++reg)
        C[(size_t)(mrow + reg) * ldc + ncol] = acc[ti][tj][reg] + bsv;
    }
  }
}

// Fused QKV projection (packed inputs): N = [q 0..2048)[k ..3072)[v ..4096)
__global__ __launch_bounds__(256) void gemm_qkv(
    const unsigned* __restrict__ hidP, const unsigned* __restrict__ wqP,
    const float* __restrict__ bq, const unsigned* __restrict__ wkP,
    const float* __restrict__ bk, const unsigned* __restrict__ wvP,
    const float* __restrict__ bv, float* __restrict__ q, float* __restrict__ k,
    float* __restrict__ v) {
  const int n0 = blockIdx.x * 128, m0 = blockIdx.y * 128;
  if (n0 < QSTRIDE) {
    gemm_split_body<4>(hidP, wqP + (size_t)n0 * H_, bq + n0, q, QSTRIDE, n0,
                       H_, m0);
  } else if (n0 < QSTRIDE + KSTRIDE) {
    int nn = n0 - QSTRIDE;
    gemm_split_body<4>(hidP, wkP + (size_t)nn * H_, bk + nn, k, KSTRIDE, nn,
                       H_, m0);
  } else {
    int nn = n0 - QSTRIDE - KSTRIDE;
    gemm_split_body<4>(hidP, wvP + (size_t)nn * H_, bv + nn, v, KSTRIDE, nn,
                       H_, m0);
  }
}

// Out-projection (packed A from attn epilogue, packed wo)
template <int TI>
__global__ __launch_bounds__(256) void gemm_split_k(
    const unsigned* __restrict__ A, const unsigned* __restrict__ W,
    const float* __restrict__ bias, float* __restrict__ C, int N, int K) {
  const int n0 = blockIdx.x * 128, m0 = blockIdx.y * (TI * 32);
  gemm_split_body<TI>(A, W + (size_t)n0 * K, bias + n0, C, N, n0, K, m0);
}

// ---------------------------------------------------------------------------
// RoPE (q,k only) + split-pack IN PLACE as (hi<<16|lo) dwords.
// grid (S, B), block 256. v handled by vtrans.
// ---------------------------------------------------------------------------
__global__ __launch_bounds__(256) void rope_pack(float* __restrict__ qtmp,
                                                 float* __restrict__ ktmp,
                                                 const int* __restrict__ pos_ids) {
  const int s = blockIdx.x, b = blockIdx.y;
  const int t = threadIdx.x;
  __shared__ float fsh[64];
  if (t < 64) fsh[t] = (float)(1.0 / pow(1.0e6, (double)t / 64.0));
  __syncthreads();
  const int pos = pos_ids[b * S_ + s];
#pragma unroll
  for (int it = 0; it < 6; ++it) {
    const int p = t + 256 * it;   // 0..1535 (slots 0..23: q then k)
    const int slot = p >> 6;      // uniform per wave
    const int d = p & 63;
    float* base = (slot < NH_)
                      ? qtmp + (size_t)(b * S_ + s) * QSTRIDE + slot * HD_
                      : ktmp + (size_t)(b * S_ + s) * KSTRIDE + (slot - NH_) * HD_;
    float x = base[d], y = base[d + 64];
    unsigned* up = (unsigned*)base;
    float ang = (float)pos * fsh[d];
    float c = cosf(ang), sn = sinf(ang);
    up[d] = packsplit(x * c - y * sn);
    up[d + 64] = packsplit(y * c + x * sn);
  }
}

// ---------------------------------------------------------------------------
// V transpose+pack: vtmp fp32 [b][s][g][d] -> vT packed u32 [b][g][d][s].
// grid (S/64, NKV, B), block 256.
// ---------------------------------------------------------------------------
__global__ __launch_bounds__(256) void vtrans(const float* __restrict__ vtmp,
                                              unsigned* __restrict__ vT) {
  const int s0 = blockIdx.x * 64;
  const int g = blockIdx.y, b = blockIdx.z;
  __shared__ unsigned tile[64][133];
  const int t = threadIdx.x;
  {
    const int row = t >> 5;        // 0..7
    const int c4 = (t & 31) * 4;   // dword col
    for (int r = 0; r < 64; r += 8) {
      const float* src =
          vtmp + ((size_t)(b * S_ + s0 + row + r) * NKV_ + g) * HD_ + c4;
      float4 xv = *(const float4*)src;
      tile[row + r][c4 + 0] = packsplit(xv.x);
      tile[row + r][c4 + 1] = packsplit(xv.y);
      tile[row + r][c4 + 2] = packsplit(xv.z);
      tile[row + r][c4 + 3] = packsplit(xv.w);
    }
  }
  __syncthreads();
  {
    const int tok4 = (t & 15) * 4;  // 0..60
    const int d0 = t >> 4;          // 0..15
    for (int dd = 0; dd < 128; dd += 16) {
      const int dim = d0 + dd;
      u32x4 o;
      o.x = tile[tok4 + 0][dim];
      o.y = tile[tok4 + 1][dim];
      o.z = tile[tok4 + 2][dim];
      o.w = tile[tok4 + 3][dim];
      *(u32x4*)&vT[(((size_t)(b * NKV_ + g) * HD_ + dim) * S_) + s0 + tok4] = o;
    }
  }
}

// ---------------------------------------------------------------------------
// Sparse attention v11 (MFMA): one block per (b, h, 16 queries), 512 threads.
// __launch_bounds__(512, 2): 128 VGPRs — the v3..v10 kernels were silently
// capped at 64 VGPRs (launch_bounds min-waves=4) and SPILLED the register
// double-buffers to scratch; occupancy stays 2 blocks/CU (LDS-limited).
// Select: ballot+popcount bisection (best measured variant).
// Epilogue writes PACKED output for the out-projection.
// ---------------------------------------------------------------------------
constexpr int SCW = 1030;   // sc row stride (pad: 1024+6)

__global__ __launch_bounds__(512, 2) void attn_kernel(
    unsigned* __restrict__ qpk, const unsigned* __restrict__ kpk,
    const unsigned* __restrict__ vTpk) {
  const int q0 = blockIdx.x * QB_;
  const int h = blockIdx.y, b = blockIdx.z, g = h / GROUPS_;
  const int t = threadIdx.x, lane = t & 63, wid = t >> 6;  // wid 0..7
  const int fm = lane & 15, quad = lane >> 4;

  __shared__ float sc[QB_ * SCW];       // 65.9 KB: fp32 scores -> packed probs
  __shared__ float redmx[8][QB_];
  __shared__ float Zsh[QB_];
  const float scale = 0.08838834764831845f;  // 1/sqrt(128)

  // ---- Q A-fragments straight from global (row fm = query within block) ----
  short8 qh[4], ql[4];
  {
    const unsigned* qrow =
        qpk + (size_t)(b * S_ + q0 + fm) * QSTRIDE + h * HD_;
#pragma unroll
    for (int ks = 0; ks < 4; ++ks) {
      u32x4 a0 = *(const u32x4*)&qrow[ks * 32 + quad * 8];
      u32x4 a1 = *(const u32x4*)&qrow[ks * 32 + quad * 8 + 4];
      unpack8r(a0, a1, qh[ks], ql[ks]);
    }
  }

  // ---- QK^T over 8 tiles of 128 keys; rolled 2-tile register dbuf ----
  const unsigned* kg = kpk + (size_t)(b * S_) * KSTRIDE + g * HD_;
  const int krow = wid * 16 + fm;  // key within tile
  const unsigned* kr0 = kg + (size_t)krow * KSTRIDE;
  u32x4 ka[8], kb[8];
  f32x4 mxacc = {-1e30f, -1e30f, -1e30f, -1e30f};

  auto k_load = [&](u32x4* kreg, int tile) {
    const unsigned* kr = kr0 + (size_t)tile * 128 * KSTRIDE;
#pragma unroll
    for (int ks = 0; ks < 4; ++ks) {
      kreg[2 * ks] = *(const u32x4*)&kr[ks * 32 + quad * 8];
      kreg[2 * ks + 1] = *(const u32x4*)&kr[ks * 32 + quad * 8 + 4];
    }
  };
  auto qk_tile = [&](const u32x4* kreg, int tile) {
    f32x4 acc = {0.f, 0.f, 0.f, 0.f};
#pragma unroll
    for (int ks = 0; ks < 4; ++ks) {
      short8 bh, bl;
      unpack8r(kreg[2 * ks], kreg[2 * ks + 1], bh, bl);
      acc = __builtin_amdgcn_mfma_f32_16x16x32_bf16(qh[ks], bh, acc, 0, 0, 0);
      acc = __builtin_amdgcn_mfma_f32_16x16x32_bf16(qh[ks], bl, acc, 0, 0, 0);
      acc = __builtin_amdgcn_mfma_f32_16x16x32_bf16(ql[ks], bh, acc, 0, 0, 0);
    }
    const int key = tile * 128 + krow;
#pragma unroll
    for (int reg = 0; reg < 4; ++reg) {
      float sval = acc[reg] * scale;
      sc[(quad * 4 + reg) * SCW + key] = sval;
      mxacc[reg] = fmaxf(mxacc[reg], sval);
    }
  };

  k_load(ka, 0);
#pragma unroll 1
  for (int tp = 0; tp < 4; ++tp) {
    k_load(kb, 2 * tp + 1);
    qk_tile(ka, 2 * tp);
    if (tp < 3) k_load(ka, 2 * tp + 2);
    qk_tile(kb, 2 * tp + 1);
  }

  // per-wave row max: reduce across fm lanes (quad bits untouched)
#pragma unroll
  for (int o = 1; o < 16; o <<= 1) {
    mxacc[0] = fmaxf(mxacc[0], __shfl_xor(mxacc[0], o));
    mxacc[1] = fmaxf(mxacc[1], __shfl_xor(mxacc[1], o));
    mxacc[2] = fmaxf(mxacc[2], __shfl_xor(mxacc[2], o));
    mxacc[3] = fmaxf(mxacc[3], __shfl_xor(mxacc[3], o));
  }
  if (fm == 0) {
#pragma unroll
    for (int reg = 0; reg < 4; ++reg) redmx[wid][quad * 4 + reg] = mxacc[reg];
  }
  __syncthreads();  // barrier 1: sc + redmx complete (all waves)

  // ---- issue V tile-0 prefetch; latency hides under the select ----
  const int dim = wid * 16 + fm;  // output dim for this lane
  const unsigned* vTr = vTpk + ((size_t)(b * NKV_ + g) * HD_ + dim) * S_;
  u32x4 va[8], vb[8];
  auto v_load = [&](u32x4* vreg, int tile) {
    const unsigned* vr = vTr + tile * 128;
#pragma unroll
    for (int ks = 0; ks < 4; ++ks) {
      vreg[2 * ks] = *(const u32x4*)&vr[ks * 32 + quad * 8];
      vreg[2 * ks + 1] = *(const u32x4*)&vr[ks * 32 + quad * 8 + 4];
    }
  };
  v_load(va, 0);

  // ---- exact top-k threshold: 32-round bisection, ballot+popcount counts ---
  // T = max{T : #(fkey >= T) >= k}  (k-th largest key; ties included)
  unsigned curA = 0u, curB = 0u;
  {
    unsigned uvA[16], uvB[16];
#pragma unroll
    for (int j = 0; j < 16; ++j)
      uvA[j] = fkey(sc[(2 * wid) * SCW + lane + 64 * j]);
#pragma unroll
    for (int j = 0; j < 16; ++j)
      uvB[j] = fkey(sc[(2 * wid + 1) * SCW + lane + 64 * j]);
#pragma unroll 1
    for (int bit = 31; bit >= 0; --bit) {
      const unsigned cA = curA | (1u << bit), cB = curB | (1u << bit);
      int cntA = 0, cntB = 0;
#pragma unroll
      for (int j = 0; j < 16; ++j)
        cntA += __popcll(__ballot(uvA[j] >= cA));
#pragma unroll
      for (int j = 0; j < 16; ++j)
        cntB += __popcll(__ballot(uvB[j] >= cB));
      if (cntA >= TOPK_) curA = cA;
      if (cntB >= TOPK_) curB = cB;
    }
  }
  const unsigned pref = (lane >= 32) ? curB : curA;  // row qi = t>>5

  // ---- masked softmax numerators; pack P in place as hi|lo dwords ----
  {
    const int qi = t >> 5, li = t & 31;  // 32 threads per query row
    const float mx =
        fmaxf(fmaxf(fmaxf(redmx[0][qi], redmx[1][qi]),
                    fmaxf(redmx[2][qi], redmx[3][qi])),
              fmaxf(fmaxf(redmx[4][qi], redmx[5][qi]),
                    fmaxf(redmx[6][qi], redmx[7][qi])));
    unsigned* scp = (unsigned*)&sc[qi * SCW];
    float zloc = 0.f;
#pragma unroll 2
    for (int j = 0; j < 8; ++j) {
      int i4 = li * 4 + 128 * j;
      f32x4 sv = *(const f32x4*)&sc[qi * SCW + i4];
      u32x4 pk;
      float p0 = (fkey(sv.x) >= pref) ? __expf(sv.x - mx) : 0.0f;
      float p1 = (fkey(sv.y) >= pref) ? __expf(sv.y - mx) : 0.0f;
      float p2 = (fkey(sv.z) >= pref) ? __expf(sv.z - mx) : 0.0f;
      float p3 = (fkey(sv.w) >= pref) ? __expf(sv.w - mx) : 0.0f;
      zloc += p0 + p1 + p2 + p3;
      pk.x = packsplit(p0); pk.y = packsplit(p1);
      pk.z = packsplit(p2); pk.w = packsplit(p3);
      *(u32x4*)&scp[i4] = pk;
    }
#pragma unroll
    for (int off = 1; off < 32; off <<= 1) zloc += __shfl_xor(zloc, off);
    if (li == 0) Zsh[qi] = zloc;
  }
  __syncthreads();  // barrier 2: packed P + Zsh visible to all waves

  // ---- P.V over 8 tiles; rolled 2-tile register dbuf (V^T contiguous) ----
  const unsigned* scp2 = (const unsigned*)sc;
  f32x4 oacc = {0.f, 0.f, 0.f, 0.f};
  auto pv_tile = [&](const u32x4* vreg, int tile) {
#pragma unroll
    for (int ks = 0; ks < 4; ++ks) {
      short8 ph, pl;
      unpack8(&scp2[fm * SCW + tile * 128 + ks * 32 + quad * 8], ph, pl);
      short8 vh, vl;
      unpack8r(vreg[2 * ks], vreg[2 * ks + 1], vh, vl);
      oacc = __builtin_amdgcn_mfma_f32_16x16x32_bf16(ph, vh, oacc, 0, 0, 0);
      oacc = __builtin_amdgcn_mfma_f32_16x16x32_bf16(ph, vl, oacc, 0, 0, 0);
      oacc = __builtin_amdgcn_mfma_f32_16x16x32_bf16(pl, vh, oacc, 0, 0, 0);
    }
  };
#pragma unroll 1
  for (int tp = 0; tp < 4; ++tp) {
    v_load(vb, 2 * tp + 1);
    pv_tile(va, 2 * tp);
    if (tp < 3) v_load(va, 2 * tp + 2);
    pv_tile(vb, 2 * tp + 1);
  }

  // ---- epilogue: write PACKED output (feeds packed out-projection) ----
#pragma unroll
  for (int reg = 0; reg < 4; ++reg) {
    const int q = quad * 4 + reg;
    const float invZ = 1.0f / Zsh[q];  // Z >= 1 structurally
    unsigned* outp = qpk + (size_t)(b * S_ + q0 + q) * QSTRIDE + h * HD_;
    outp[dim] = packsplit(oacc[reg] * invZ);
  }
}

// ---------------------------------------------------------------------------
extern "C" void kernel_launch(void* const* d_in, const int* in_sizes, int n_in,
                              void* d_out, int out_size, void* d_ws,
                              size_t ws_size, hipStream_t stream) {
  // All tensors are float32 per the reference; position_ids is int32.
  const float* hidden = (const float*)d_in[0];
  const float* wq = (const float*)d_in[1];
  const float* bq = (const float*)d_in[2];
  const float* wk = (const float*)d_in[3];
  const float* bk = (const float*)d_in[4];
  const float* wv = (const float*)d_in[5];
  const float* bv = (const float*)d_in[6];
  const float* wo = (const float*)d_in[7];
  const float* bo = (const float*)d_in[8];
  const int* pos = (const int*)d_in[9];
  float* out = (float*)d_out;

  char* ws = (char*)d_ws;
  // ws layout (96 MB):
  //  0..16  hidP   (packed hidden)
  // 16..32  wqP    (packed wq)      -> reused as vT (8 MB) after gemm_qkv
  // 32..40  wkP    (packed wk)
  // 40..48  wvP    (packed wv)
  // 48..64  woP    (packed wo; live until out-proj)
  // 64..80  qtmp   (fp32 q -> rope-packed -> attn writes packed out in place)
  // 80..88  ktmp   (fp32 k -> rope-packed)
  // 88..96  vtmp   (fp32 v)
  unsigned* hidP = (unsigned*)(ws);
  unsigned* wqP = (unsigned*)(ws + ((size_t)16 << 20));
  unsigned* wkP = (unsigned*)(ws + ((size_t)32 << 20));
  unsigned* wvP = (unsigned*)(ws + ((size_t)40 << 20));
  unsigned* woP = (unsigned*)(ws + ((size_t)48 << 20));
  float* qtmp = (float*)(ws + ((size_t)64 << 20));
  float* ktmp = (float*)(ws + ((size_t)80 << 20));
  float* vtmp = (float*)(ws + ((size_t)88 << 20));
  unsigned* vT = (unsigned*)(ws + ((size_t)16 << 20));  // over wqP (dead)

  dim3 blk(256);
  // One-pass split-bf16 packing of all GEMM inputs (bit-identical math)
  pack_inputs<<<dim3(16384), blk, 0, stream>>>(hidden, wq, wk, wv, wo, hidP,
                                               wqP, wkP, wvP, woP);
  // Fused QKV projection (packed inputs): grid 32x16 = 512 blocks (2/CU)
  gemm_qkv<<<dim3(32, 16), blk, 0, stream>>>(hidP, wqP, bq, wkP, bk, wvP, bv,
                                             qtmp, ktmp, vtmp);
  // RoPE + in-place split-pack of q, k
  rope_pack<<<dim3(S_, B_), blk, 0, stream>>>(qtmp, ktmp, pos);
  // V transpose + pack (into the dead wqP region)
  vtrans<<<dim3(S_ / 64, NKV_, B_), blk, 0, stream>>>(vtmp, vT);
  // MFMA sparse attention: 16 queries/block, 512 threads, grid 64x16x2
  attn_kernel<<<dim3(S_ / QB_, NH_, B_), dim3(512), 0, stream>>>(
      (unsigned*)qtmp, (const unsigned*)ktmp, vT);
  // Output projection (packed A + packed wo): grid 16x32 = 512 blocks
  gemm_split_k<2><<<dim3(H_ / 128, (B_ * S_) / 64), blk, 0, stream>>>(
      (const unsigned*)qtmp, woP, bo, out, H_, H_);
}